// Round 1
// baseline (546.475 us; speedup 1.0000x reference)
//
#include <hip/hip_runtime.h>
#include <math.h>

#define BATCH 128
#define SEQ 64
#define IN 320
#define OUT 64
#define ITEM 256
#define HID 1024
#define OH 192
#define T65 65

// ---------------------------------------------------------------------------
// Kernel 1: G[b][t][h] = W_hi[b,h,:] . xs[b,t,:]  (t=0..63 = x_item rows, t=64 = x_q)
//           X[b][t][s] = x_item[b,s,:] . xs[b,t,:]   (extra tile, tile==16)
// grid (17, 128), block 256 (4 waves). Wave wv handles t in [wv*16, wv*16+16),
// wave 0 additionally t=64. lane = row within the 64-row tile.
// ---------------------------------------------------------------------------
__global__ __launch_bounds__(256) void k_gemm(
    const float* __restrict__ W_hi, const float* __restrict__ x_c,
    const float* __restrict__ x_q, float* __restrict__ G, float* __restrict__ X)
{
  const int b = blockIdx.y;
  const int tile = blockIdx.x;                 // 0..16
  const int tid = threadIdx.x;
  const int lane = tid & 63;
  const int wv = __builtin_amdgcn_readfirstlane(tid >> 6);
  const bool isW = (tile < 16);

  __shared__ float Ws[64][65];                 // rows x k, stride 65 -> bank (lane+k)%32

  const float* rowbase;
  int rstride;
  if (isW) { rowbase = W_hi + ((size_t)b * HID + (size_t)tile * 64) * ITEM; rstride = ITEM; }
  else     { rowbase = x_c + (size_t)b * SEQ * IN;                           rstride = IN; }

  const float* xs = x_c + (size_t)b * SEQ * IN;   // t rows, stride IN, cols 0..255
  const float* xq = x_q + (size_t)b * ITEM;

  float acc[17];
  #pragma unroll
  for (int i = 0; i < 17; ++i) acc[i] = 0.f;

  const int t0 = wv * 16;

  for (int kc = 0; kc < ITEM; kc += 64) {
    __syncthreads();
    {
      const int r = tid >> 4;                   // 0..15
      const int k4 = (tid & 15) << 2;           // 0..60
      #pragma unroll
      for (int p = 0; p < 4; ++p) {
        const int rr = r + (p << 4);
        const float4 w = *reinterpret_cast<const float4*>(rowbase + (size_t)rr * rstride + kc + k4);
        Ws[rr][k4 + 0] = w.x; Ws[rr][k4 + 1] = w.y;
        Ws[rr][k4 + 2] = w.z; Ws[rr][k4 + 3] = w.w;
      }
    }
    __syncthreads();
    #pragma unroll 4
    for (int k = 0; k < 64; k += 4) {
      const float w0 = Ws[lane][k + 0];
      const float w1 = Ws[lane][k + 1];
      const float w2 = Ws[lane][k + 2];
      const float w3 = Ws[lane][k + 3];
      #pragma unroll
      for (int j = 0; j < 16; ++j) {
        const float4 xv = *reinterpret_cast<const float4*>(xs + (size_t)(t0 + j) * IN + kc + k);
        acc[j] = fmaf(w3, xv.w, fmaf(w2, xv.z, fmaf(w1, xv.y, fmaf(w0, xv.x, acc[j]))));
      }
      if (wv == 0) {
        const float4 xv = *reinterpret_cast<const float4*>(xq + kc + k);
        acc[16] = fmaf(w3, xv.w, fmaf(w2, xv.z, fmaf(w1, xv.y, fmaf(w0, xv.x, acc[16]))));
      }
    }
  }

  if (isW) {
    const int h = tile * 64 + lane;
    #pragma unroll
    for (int j = 0; j < 16; ++j)
      G[((size_t)b * T65 + (t0 + j)) * HID + h] = acc[j];
    if (wv == 0)
      G[((size_t)b * T65 + 64) * HID + h] = acc[16];
  } else {
    const int s = lane;
    #pragma unroll
    for (int j = 0; j < 16; ++j)
      X[((size_t)b * T65 + (t0 + j)) * SEQ + s] = acc[j];
    if (wv == 0)
      X[((size_t)b * T65 + 64) * SEQ + s] = acc[16];
  }
}

// ---------------------------------------------------------------------------
// Kernel 2: sequential one-winner scan per batch. grid 128, block 256.
// value(h,t) = lastw[h]<0 ? G[b][t][h] : X[b][t][lastw[h]]
// argmax with first-index (lowest h) tie-break, matching jnp.argmax.
// Then query logits, softmax, a_mod (touched zeroed), touched compaction.
// ---------------------------------------------------------------------------
__global__ __launch_bounds__(256) void k_scan(
    const float* __restrict__ G, const float* __restrict__ X,
    float* __restrict__ a_mod, int* __restrict__ t_s, float* __restrict__ t_a,
    int* __restrict__ t_n)
{
  const int b = blockIdx.x;
  const int tid = threadIdx.x;
  const int lane = tid & 63;
  const int wv = tid >> 6;

  __shared__ float Xs[T65 * SEQ];   // [t][s]
  __shared__ int lastw[HID];
  __shared__ float rv[4];
  __shared__ int rh[4];
  __shared__ float redm[4];
  __shared__ float reds[4];
  __shared__ int cnt;

  for (int i = tid; i < T65 * SEQ; i += 256)
    Xs[i] = X[(size_t)b * (T65 * SEQ) + i];
  #pragma unroll
  for (int i = 0; i < 4; ++i) lastw[tid + (i << 8)] = -1;
  if (tid == 0) cnt = 0;
  __syncthreads();

  float gcur[4];
  {
    const float* G0 = G + (size_t)b * T65 * HID;
    #pragma unroll
    for (int i = 0; i < 4; ++i) gcur[i] = G0[tid + (i << 8)];
  }

  for (int t = 0; t < SEQ; ++t) {
    // prefetch next step's (or query) G row while we reduce this step
    const float* Gn = G + ((size_t)b * T65 + (t + 1)) * HID;
    float gnext[4];
    #pragma unroll
    for (int i = 0; i < 4; ++i) gnext[i] = Gn[tid + (i << 8)];

    float bv = -1e30f; int bh = 0;
    #pragma unroll
    for (int i = 0; i < 4; ++i) {
      const int h = tid + (i << 8);
      const int lw = lastw[h];
      const int idx = lw < 0 ? 0 : lw;
      const float xv = Xs[t * SEQ + idx];
      const float v = (lw < 0) ? gcur[i] : xv;
      if (v > bv || (v == bv && h < bh)) { bv = v; bh = h; }
    }
    #pragma unroll
    for (int m = 1; m < 64; m <<= 1) {
      const float ov = __shfl_xor(bv, m, 64);
      const int oh = __shfl_xor(bh, m, 64);
      if (ov > bv || (ov == bv && oh < bh)) { bv = ov; bh = oh; }
    }
    if (lane == 0) { rv[wv] = bv; rh[wv] = bh; }
    __syncthreads();
    if (tid == 0) {
      float fv = rv[0]; int fh = rh[0];
      #pragma unroll
      for (int w = 1; w < 4; ++w)
        if (rv[w] > fv || (rv[w] == fv && rh[w] < fh)) { fv = rv[w]; fh = rh[w]; }
      lastw[fh] = t;
    }
    __syncthreads();
    #pragma unroll
    for (int i = 0; i < 4; ++i) gcur[i] = gnext[i];
  }

  // gcur now holds G[b][64][*] (query logits for untouched rows)
  float l[4]; int lw4[4];
  #pragma unroll
  for (int i = 0; i < 4; ++i) {
    const int h = tid + (i << 8);
    const int lw = lastw[h];
    lw4[i] = lw;
    const int idx = lw < 0 ? 0 : lw;
    l[i] = (lw < 0) ? gcur[i] : Xs[64 * SEQ + idx];
  }
  float mx = fmaxf(fmaxf(l[0], l[1]), fmaxf(l[2], l[3]));
  #pragma unroll
  for (int m = 1; m < 64; m <<= 1) mx = fmaxf(mx, __shfl_xor(mx, m, 64));
  if (lane == 0) redm[wv] = mx;
  __syncthreads();
  const float M = fmaxf(fmaxf(redm[0], redm[1]), fmaxf(redm[2], redm[3]));
  float e[4];
  float ssum = 0.f;
  #pragma unroll
  for (int i = 0; i < 4; ++i) { e[i] = expf(l[i] - M); ssum += e[i]; }
  #pragma unroll
  for (int m = 1; m < 64; m <<= 1) ssum += __shfl_xor(ssum, m, 64);
  if (lane == 0) reds[wv] = ssum;
  __syncthreads();
  const float S = reds[0] + reds[1] + reds[2] + reds[3];
  const float inv = 1.f / S;
  #pragma unroll
  for (int i = 0; i < 4; ++i) {
    const int h = tid + (i << 8);
    const float a = e[i] * inv;
    float am = a;
    if (lw4[i] >= 0) {
      am = 0.f;
      const int slot = atomicAdd(&cnt, 1);
      t_s[b * SEQ + slot] = lw4[i];
      t_a[b * SEQ + slot] = a;
    }
    a_mod[(size_t)b * HID + h] = am;
  }
  __syncthreads();
  if (tid == 0) t_n[b] = cnt;
}

// ---------------------------------------------------------------------------
// Kernel 3: partial matvecs with a_mod (touched rows zeroed).
// grid (4, 128), block 256. h-range [p*256, p*256+256).
// waves 0-2: reinst partial (c = tid, 0..191); wave 3: out partial (64 o's).
// ---------------------------------------------------------------------------
__global__ __launch_bounds__(256) void k_partial(
    const float* __restrict__ W_oh, const float* __restrict__ W_re,
    const float* __restrict__ a_mod, float* __restrict__ p_out, float* __restrict__ p_re)
{
  const int b = blockIdx.y;
  const int p = blockIdx.x;
  const int tid = threadIdx.x;
  const int h0 = p * 256;
  __shared__ float as[256];
  as[tid] = a_mod[(size_t)b * HID + h0 + tid];
  __syncthreads();

  const int wv = tid >> 6, lane = tid & 63;
  if (wv < 3) {
    const int c = tid;   // 0..191
    const float* Wr = W_re + ((size_t)b * HID + h0) * OH + c;
    float acc = 0.f;
    #pragma unroll 8
    for (int h = 0; h < 256; ++h)
      acc = fmaf(Wr[(size_t)h * OH], as[h], acc);
    p_re[((size_t)b * 4 + p) * OH + c] = acc;
  } else {
    for (int o = 0; o < 64; ++o) {
      const float4 w4 = *reinterpret_cast<const float4*>(
          W_oh + ((size_t)b * OUT + o) * HID + h0 + lane * 4);
      const float* ap = &as[lane * 4];
      float acc = w4.x * ap[0] + w4.y * ap[1] + w4.z * ap[2] + w4.w * ap[3];
      #pragma unroll
      for (int m = 1; m < 64; m <<= 1) acc += __shfl_xor(acc, m, 64);
      if (lane == 0) p_out[((size_t)b * 4 + p) * OUT + o] = acc;
    }
  }
}

// ---------------------------------------------------------------------------
// Kernel 4: combine partials + touched-row corrections -> d_out.
// grid 128, block 256. tid<64: out[b][o]; tid 64..255: reinst[b][c].
// ---------------------------------------------------------------------------
__global__ __launch_bounds__(256) void k_final(
    const float* __restrict__ x_c, const float* __restrict__ ctx,
    const float* __restrict__ p_out, const float* __restrict__ p_re,
    const int* __restrict__ t_s, const float* __restrict__ t_a,
    const int* __restrict__ t_n, float* __restrict__ out)
{
  const int b = blockIdx.x;
  const int tid = threadIdx.x;
  __shared__ int ss[64];
  __shared__ float sa[64];
  __shared__ int n_s;
  if (tid == 0) n_s = t_n[b];
  if (tid < 64) { ss[tid] = t_s[b * SEQ + tid]; sa[tid] = t_a[b * SEQ + tid]; }
  __syncthreads();
  const int n = n_s;
  if (tid < 64) {
    const int o = tid;
    float acc = 0.f;
    #pragma unroll
    for (int p = 0; p < 4; ++p) acc += p_out[((size_t)b * 4 + p) * OUT + o];
    for (int j = 0; j < n; ++j)
      acc = fmaf(x_c[((size_t)b * SEQ + ss[j]) * IN + ITEM + o], sa[j], acc);
    out[(size_t)b * OUT + o] = acc;
  } else {
    const int c = tid - 64;  // 0..191
    float acc = 0.f;
    #pragma unroll
    for (int p = 0; p < 4; ++p) acc += p_re[((size_t)b * 4 + p) * OH + c];
    for (int j = 0; j < n; ++j)
      acc = fmaf(ctx[((size_t)b * SEQ + ss[j]) * OH + c], sa[j], acc);
    out[(size_t)BATCH * OUT + (size_t)b * OH + c] = acc;
  }
}

// ---------------------------------------------------------------------------
extern "C" void kernel_launch(void* const* d_in, const int* in_sizes, int n_in,
                              void* d_out, int out_size, void* d_ws, size_t ws_size,
                              hipStream_t stream)
{
  const float* x_c  = (const float*)d_in[0];   // 128 x 64 x 320
  const float* x_q  = (const float*)d_in[1];   // 128 x 256
  const float* ctx  = (const float*)d_in[2];   // 128 x 64 x 192
  const float* W_hi = (const float*)d_in[3];   // 128 x 1024 x 256
  const float* W_oh = (const float*)d_in[4];   // 128 x 64 x 1024
  const float* W_re = (const float*)d_in[5];   // 128 x 1024 x 192

  char* ws = (char*)d_ws;
  float* G     = (float*)(ws);                 // 128*65*1024*4  = 34,078,720
  float* X     = (float*)(ws + 34078720);      // 128*65*64*4    =  2,129,920
  float* a_mod = (float*)(ws + 36208640);      // 128*1024*4     =    524,288
  int*   t_s   = (int*)  (ws + 36732928);      // 128*64*4
  float* t_a   = (float*)(ws + 36765696);      // 128*64*4
  int*   t_n   = (int*)  (ws + 36798464);      // 128*4
  float* p_out = (float*)(ws + 36798976);      // 128*4*64*4
  float* p_re  = (float*)(ws + 36930048);      // 128*4*192*4    -> end 37,323,264

  k_gemm<<<dim3(17, BATCH), 256, 0, stream>>>(W_hi, x_c, x_q, G, X);
  k_scan<<<dim3(BATCH), 256, 0, stream>>>(G, X, a_mod, t_s, t_a, t_n);
  k_partial<<<dim3(4, BATCH), 256, 0, stream>>>(W_oh, W_re, a_mod, p_out, p_re);
  k_final<<<dim3(BATCH), 256, 0, stream>>>(x_c, ctx, p_out, p_re, t_s, t_a, t_n, (float*)d_out);
}